// Round 7
// baseline (184.289 us; speedup 1.0000x reference)
//
#include <hip/hip_runtime.h>
#include <math.h>

// GMM EM, M=4 mixtures x G=4 gaussians, C=3, EM_ITERS=3, EPS=1e-4.
// R7: all quad-level cross-lane traffic moved from ds_bpermute/__shfl (per-CU
// LDS pipe + lgkmcnt stalls -- the R6 ~35us/kernel mystery) to DPP quad_perm
// broadcasts (pure VALU). Role lane q = lane&3 owns mixture q: params PR[40]
// and stats acc[40] in registers; hot loops contain ZERO DS instructions.
// Cross-block combine: shfl_xor wave reduce -> LDS -> banked global
// unsafeAtomicAdd (HW fadd, verified R5/R6). Every block of the next dispatch
// redundantly derives the 16x12 params from the 160 sums.
// Pipeline: memset(7.7KB) -> accum0 -> accum(em) -> accum(em) -> final.

#define NTHR  256
#define NBLK  1024
#define EPS_F 1e-4f
#define LOG2PI3 5.5136311992280366f   // 3*ln(2*pi)

// quad_perm broadcast: every lane gets value of lane (lane & ~3) + S
template <int S>
static __device__ __forceinline__ float qbcast(float v) {
    return __int_as_float(__builtin_amdgcn_update_dpp(
        0, __float_as_int(v), (S * 0x55), 0xF, 0xF, true));
}
template <int S>
static __device__ __forceinline__ int qbcast_i(int v) {
    return __builtin_amdgcn_update_dpp(0, v, (S * 0x55), 0xF, 0xF, true);
}

// sums buffer per pass: [160 slots][4 banks] floats (slot = (m*4+g)*10+k)

// Derive E-step params from banked sums. spar layout per cluster t, stride 12:
// [0..2]=P*mu, [3]=c0, [4..6]=-0.5*Pii, [7..9]=-Pij(01,02,12), [10..11]=pad
static __device__ void compute_params(const float* __restrict__ sumsIn,
                                      float* spar, float* sums, float* wtab,
                                      int tid) {
    if (tid < 160) {
        float4 v = ((const float4*)sumsIn)[tid];   // 4 banks -> horizontal add
        sums[tid] = (v.x + v.y) + (v.z + v.w);
    }
    __syncthreads();
    if (tid < 16) wtab[tid] = sums[tid * 10] + EPS_F;
    __syncthreads();
    if (tid < 16) {
        const int tt = tid;
        const float* S = &sums[tt * 10];
        const float w  = wtab[tt];
        const float iw = 1.0f / w;
        float mu0 = S[1] * iw, mu1 = S[2] * iw, mu2 = S[3] * iw;
        float c00 = S[4] * iw - mu0 * mu0 + EPS_F;
        float c01 = S[5] * iw - mu0 * mu1;
        float c02 = S[6] * iw - mu0 * mu2;
        float c11 = S[7] * iw - mu1 * mu1 + EPS_F;
        float c12 = S[8] * iw - mu1 * mu2;
        float c22 = S[9] * iw - mu2 * mu2 + EPS_F;
        float d00 = c11 * c22 - c12 * c12;
        float d01 = c02 * c12 - c01 * c22;
        float d02 = c01 * c12 - c02 * c11;
        float det = c00 * d00 + c01 * d01 + c02 * d02;
        float idet = 1.0f / det;
        float P00 = d00 * idet, P01 = d01 * idet, P02 = d02 * idet;
        float P11 = (c00 * c22 - c02 * c02) * idet;
        float P12 = (c01 * c02 - c00 * c12) * idet;
        float P22 = (c00 * c11 - c01 * c01) * idet;
        float logdet = logf(det);
        const int mb = tt & 12;
        float wsum = wtab[mb] + wtab[mb + 1] + wtab[mb + 2] + wtab[mb + 3];
        float logpi = logf(w) - logf(wsum);
        float pm0 = P00 * mu0 + P01 * mu1 + P02 * mu2;
        float pm1 = P01 * mu0 + P11 * mu1 + P12 * mu2;
        float pm2 = P02 * mu0 + P12 * mu1 + P22 * mu2;
        float mPm = mu0 * pm0 + mu1 * pm1 + mu2 * pm2;
        float c0 = logpi - 0.5f * (mPm + logdet + LOG2PI3);
        float* P = spar + tt * 12;
        P[0] = pm0; P[1] = pm1; P[2] = pm2; P[3] = c0;
        P[4] = -0.5f * P00; P[5] = -0.5f * P11; P[6] = -0.5f * P22;
        P[7] = -P01; P[8] = -P02; P[9] = -P12;
        P[10] = 0.f; P[11] = 0.f;
    }
    __syncthreads();
}

// shared epilogue: wave-reduce acc[40] over role classes, cross-wave, global fadd
static __device__ __forceinline__ void reduce_out(float* acc, float (*sred)[160],
                                                  float* __restrict__ sumsOut,
                                                  int tid, int wave, int lane) {
    #pragma unroll
    for (int k = 0; k < 40; ++k) {
        float v = acc[k];
        v += __shfl_xor(v,  4, 64);
        v += __shfl_xor(v,  8, 64);
        v += __shfl_xor(v, 16, 64);
        v += __shfl_xor(v, 32, 64);
        acc[k] = v;
    }
    if (lane < 4) {                      // lane == mixture q; slot = q*40 + idx
        #pragma unroll
        for (int k = 0; k < 40; ++k) sred[wave][lane * 40 + k] = acc[k];
    }
    __syncthreads();
    if (tid < 160) {
        float s = sred[0][tid] + sred[1][tid] + sred[2][tid] + sred[3][tid];
        unsafeAtomicAdd(&sumsOut[tid * 4 + 0], s);   // HW global fadd
    }
}

// ---------- init stats: resp = onehot(m = label) x onehot(g = n%4) ----------
__global__ __launch_bounds__(NTHR, 2) void k_accum0(const float* __restrict__ x,
                                                    const int* __restrict__ lab,
                                                    float* __restrict__ sumsOut,
                                                    int N) {
    __shared__ float sred[NTHR / 64][160];
    const int tid  = threadIdx.x;
    const int wave = tid >> 6, lane = tid & 63;
    const int q    = lane & 3;

    float acc[40];
    #pragma unroll
    for (int k = 0; k < 40; ++k) acc[k] = 0.f;

    const int groups = N >> 2;
    const int stride = gridDim.x * NTHR;
    const int gid    = blockIdx.x * NTHR + tid;
    const float4* x0p = (const float4*)x;
    const float4* x1p = (const float4*)(x + N);
    const float4* x2p = (const float4*)(x + 2 * N);
    const int4*   lp  = (const int4*)lab;

    for (int i = gid; i < groups; i += stride) {
        float4 va = x0p[i], vb = x1p[i], vc = x2p[i];
        int4   m4 = lp[i];
        float pa[4] = {va.x, va.y, va.z, va.w};
        float pb[4] = {vb.x, vb.y, vb.z, vb.w};
        float pc[4] = {vc.x, vc.y, vc.z, vc.w};
        int   pm[4] = {m4.x, m4.y, m4.z, m4.w};
        #pragma unroll
        for (int j = 0; j < 4; ++j) {     // pixel n = 4*i+j -> gaussian j
            const float a = pa[j], b = pb[j], c = pc[j];
            const int   m = pm[j];
            float ra[4], rb[4], rc[4]; int rm[4];
            ra[0]=qbcast<0>(a); rb[0]=qbcast<0>(b); rc[0]=qbcast<0>(c); rm[0]=qbcast_i<0>(m);
            ra[1]=qbcast<1>(a); rb[1]=qbcast<1>(b); rc[1]=qbcast<1>(c); rm[1]=qbcast_i<1>(m);
            ra[2]=qbcast<2>(a); rb[2]=qbcast<2>(b); rc[2]=qbcast<2>(c); rm[2]=qbcast_i<2>(m);
            ra[3]=qbcast<3>(a); rb[3]=qbcast<3>(b); rc[3]=qbcast<3>(c); rm[3]=qbcast_i<3>(m);
            #pragma unroll
            for (int p = 0; p < 4; ++p) {
                if (rm[p] == q) {        // exec-masked; empty -> execz skip
                    const float A = ra[p], B = rb[p], C = rc[p];
                    float* Q = &acc[j * 10];
                    Q[0] += 1.f;
                    Q[1] += A;  Q[2] += B;  Q[3] += C;
                    Q[4] = fmaf(A, A, Q[4]);
                    Q[5] = fmaf(A, B, Q[5]);
                    Q[6] = fmaf(A, C, Q[6]);
                    Q[7] = fmaf(B, B, Q[7]);
                    Q[8] = fmaf(B, C, Q[8]);
                    Q[9] = fmaf(C, C, Q[9]);
                }
            }
        }
    }
    reduce_out(acc, sred, sumsOut, tid, wave, lane);
}

// ---------- EM step: E (own-mixture softmax) + M stats, params in regs ----------
__global__ __launch_bounds__(NTHR, 2) void k_accum(const float* __restrict__ x,
                                                   const int* __restrict__ lab,
                                                   const float* __restrict__ sumsIn,
                                                   float* __restrict__ sumsOut,
                                                   int N) {
    __shared__ __align__(16) float spar[192];
    __shared__ float sums[160];
    __shared__ float wtab[16];
    __shared__ float sred[NTHR / 64][160];
    const int tid  = threadIdx.x;
    const int wave = tid >> 6, lane = tid & 63;
    const int q    = lane & 3;          // my role: mixture q
    compute_params(sumsIn, spar, sums, wtab, tid);

    float PR[40];                        // my mixture's 4 gaussians x 10 coeffs
    #pragma unroll
    for (int g = 0; g < 4; ++g)
        #pragma unroll
        for (int k = 0; k < 10; ++k) PR[g * 10 + k] = spar[q * 48 + g * 12 + k];

    float acc[40];
    #pragma unroll
    for (int k = 0; k < 40; ++k) acc[k] = 0.f;

    const int groups = N >> 2;
    const int stride = gridDim.x * NTHR;
    const int gid    = blockIdx.x * NTHR + tid;
    const float4* x0p = (const float4*)x;
    const float4* x1p = (const float4*)(x + N);
    const float4* x2p = (const float4*)(x + 2 * N);
    const int4*   lp  = (const int4*)lab;

    for (int i = gid; i < groups; i += stride) {
        float4 va = x0p[i], vb = x1p[i], vc = x2p[i];
        int4   m4 = lp[i];
        float pa[4] = {va.x, va.y, va.z, va.w};
        float pb[4] = {vb.x, vb.y, vb.z, vb.w};
        float pc[4] = {vc.x, vc.y, vc.z, vc.w};
        int   pm[4] = {m4.x, m4.y, m4.z, m4.w};
        #pragma unroll
        for (int j = 0; j < 4; ++j) {
            const float a = pa[j], b = pb[j], c = pc[j];
            const int   m = pm[j];
            float ra[4], rb[4], rc[4]; int rm[4];
            ra[0]=qbcast<0>(a); rb[0]=qbcast<0>(b); rc[0]=qbcast<0>(c); rm[0]=qbcast_i<0>(m);
            ra[1]=qbcast<1>(a); rb[1]=qbcast<1>(b); rc[1]=qbcast<1>(c); rm[1]=qbcast_i<1>(m);
            ra[2]=qbcast<2>(a); rb[2]=qbcast<2>(b); rc[2]=qbcast<2>(c); rm[2]=qbcast_i<2>(m);
            ra[3]=qbcast<3>(a); rb[3]=qbcast<3>(b); rc[3]=qbcast<3>(c); rm[3]=qbcast_i<3>(m);
            #pragma unroll
            for (int p = 0; p < 4; ++p) {
                if (rm[p] == q) {        // only this pixel's mixture-owner works
                    const float A = ra[p], B = rb[p], C = rc[p];
                    const float aa = A * A, ab = A * B, ac = A * C;
                    const float bb = B * B, bc = B * C, cc = C * C;
                    float l[4];
                    #pragma unroll
                    for (int g = 0; g < 4; ++g) {
                        const float* P = &PR[g * 10];
                        l[g] = P[3] + P[0] * A + P[1] * B + P[2] * C
                             + P[4] * aa + P[5] * bb + P[6] * cc
                             + P[7] * ab + P[8] * ac + P[9] * bc;
                    }
                    float mx = fmaxf(fmaxf(l[0], l[1]), fmaxf(l[2], l[3]));
                    float e0 = __expf(l[0] - mx), e1 = __expf(l[1] - mx);
                    float e2 = __expf(l[2] - mx), e3 = __expf(l[3] - mx);
                    float rs = 1.0f / (e0 + e1 + e2 + e3);
                    float w[4] = {e0 * rs, e1 * rs, e2 * rs, e3 * rs};
                    #pragma unroll
                    for (int g = 0; g < 4; ++g) {
                        const float s = w[g];
                        float* Q = &acc[g * 10];
                        Q[0] += s;
                        Q[1] = fmaf(s, A,  Q[1]);
                        Q[2] = fmaf(s, B,  Q[2]);
                        Q[3] = fmaf(s, C,  Q[3]);
                        Q[4] = fmaf(s, aa, Q[4]);
                        Q[5] = fmaf(s, ab, Q[5]);
                        Q[6] = fmaf(s, ac, Q[6]);
                        Q[7] = fmaf(s, bb, Q[7]);
                        Q[8] = fmaf(s, bc, Q[8]);
                        Q[9] = fmaf(s, cc, Q[9]);
                    }
                }
            }
        }
    }
    reduce_out(acc, sred, sumsOut, tid, wave, lane);
}

// ---------- final: all 16 gaussians -> logsumexp_g -> softmax_m ----------
__global__ __launch_bounds__(NTHR, 2) void k_final(const float* __restrict__ x,
                                                   const float* __restrict__ sumsIn,
                                                   float* __restrict__ out,
                                                   int N) {
    __shared__ __align__(16) float spar[192];
    __shared__ float sums[160];
    __shared__ float wtab[16];
    compute_params(sumsIn, spar, sums, wtab, threadIdx.x);
    const int lane = threadIdx.x & 63;
    const int q    = lane & 3;          // my role: mixture q
    float PR[40];
    #pragma unroll
    for (int g = 0; g < 4; ++g)
        #pragma unroll
        for (int k = 0; k < 10; ++k) PR[g * 10 + k] = spar[q * 48 + g * 12 + k];

    const int groups = N >> 2;
    const int stride = gridDim.x * NTHR;
    const int gid    = blockIdx.x * NTHR + threadIdx.x;
    const float4* x0p = (const float4*)x;
    const float4* x1p = (const float4*)(x + N);
    const float4* x2p = (const float4*)(x + 2 * N);

    for (int i = gid; i < groups; i += stride) {
        float4 va = x0p[i], vb = x1p[i], vc = x2p[i];
        float pa[4] = {va.x, va.y, va.z, va.w};
        float pb[4] = {vb.x, vb.y, vb.z, vb.w};
        float pc[4] = {vc.x, vc.y, vc.z, vc.w};
        float po[4][4];                  // [j][mixture]
        #pragma unroll
        for (int j = 0; j < 4; ++j) {
            const float a = pa[j], b = pb[j], c = pc[j];
            float M[4];                  // ml_{my mixture}(quad pixel p)
            #pragma unroll
            for (int p = 0; p < 4; ++p) {
                float A, B, C;
                if (p == 0) { A=qbcast<0>(a); B=qbcast<0>(b); C=qbcast<0>(c); }
                if (p == 1) { A=qbcast<1>(a); B=qbcast<1>(b); C=qbcast<1>(c); }
                if (p == 2) { A=qbcast<2>(a); B=qbcast<2>(b); C=qbcast<2>(c); }
                if (p == 3) { A=qbcast<3>(a); B=qbcast<3>(b); C=qbcast<3>(c); }
                const float aa = A * A, ab = A * B, ac = A * C;
                const float bb = B * B, bc = B * C, cc = C * C;
                float l[4];
                #pragma unroll
                for (int g = 0; g < 4; ++g) {
                    const float* P = &PR[g * 10];
                    l[g] = P[3] + P[0] * A + P[1] * B + P[2] * C
                         + P[4] * aa + P[5] * bb + P[6] * cc
                         + P[7] * ab + P[8] * ac + P[9] * bc;
                }
                float mx = fmaxf(fmaxf(l[0], l[1]), fmaxf(l[2], l[3]));
                M[p] = mx + __logf(__expf(l[0] - mx) + __expf(l[1] - mx)
                                 + __expf(l[2] - mx) + __expf(l[3] - mx));
            }
            // quad transpose via DPP: W[qq] = ml_{qq}(my own pixel slot q)
            float W[4];
            #pragma unroll
            for (int qq = 0; qq < 4; ++qq) {
                float v0, v1, v2, v3;
                if (qq == 0) { v0=qbcast<0>(M[0]); v1=qbcast<0>(M[1]); v2=qbcast<0>(M[2]); v3=qbcast<0>(M[3]); }
                if (qq == 1) { v0=qbcast<1>(M[0]); v1=qbcast<1>(M[1]); v2=qbcast<1>(M[2]); v3=qbcast<1>(M[3]); }
                if (qq == 2) { v0=qbcast<2>(M[0]); v1=qbcast<2>(M[1]); v2=qbcast<2>(M[2]); v3=qbcast<2>(M[3]); }
                if (qq == 3) { v0=qbcast<3>(M[0]); v1=qbcast<3>(M[1]); v2=qbcast<3>(M[2]); v3=qbcast<3>(M[3]); }
                W[qq] = (q == 0) ? v0 : ((q == 1) ? v1 : ((q == 2) ? v2 : v3));
            }
            float mmx = fmaxf(fmaxf(W[0], W[1]), fmaxf(W[2], W[3]));
            float e0 = __expf(W[0] - mmx), e1 = __expf(W[1] - mmx);
            float e2 = __expf(W[2] - mmx), e3 = __expf(W[3] - mmx);
            float rs = 1.0f / (e0 + e1 + e2 + e3);
            po[j][0] = e0 * rs; po[j][1] = e1 * rs;
            po[j][2] = e2 * rs; po[j][3] = e3 * rs;
        }
        #pragma unroll
        for (int m = 0; m < 4; ++m) {
            ((float4*)(out + (size_t)m * N))[i] =
                make_float4(po[0][m], po[1][m], po[2][m], po[3][m]);
        }
    }
}

extern "C" void kernel_launch(void* const* d_in, const int* in_sizes, int n_in,
                              void* d_out, int out_size, void* d_ws, size_t ws_size,
                              hipStream_t stream) {
    const float* x   = (const float*)d_in[0];   // [3, N] float32
    const int*   lab = (const int*)d_in[1];     // [N] int32 in [0,4)
    float* out = (float*)d_out;                 // [4, N] float32
    const int N = in_sizes[1];

    float* sums = (float*)d_ws;                 // [3 passes][160 slots][4 banks]
    hipMemsetAsync(sums, 0, 3 * 640 * sizeof(float), stream);

    dim3 grid(NBLK), blk(NTHR);
    k_accum0<<<grid, blk, 0, stream>>>(x, lab, sums, N);
    k_accum <<<grid, blk, 0, stream>>>(x, lab, sums, sums + 640, N);
    k_accum <<<grid, blk, 0, stream>>>(x, lab, sums + 640, sums + 1280, N);
    k_final <<<grid, blk, 0, stream>>>(x, sums + 1280, out, N);
}